// Round 5
// baseline (127.823 us; speedup 1.0000x reference)
//
#include <hip/hip_runtime.h>
#include <math.h>

#define NB_ERB 32
#define NB_DF 96
#define EMB 256

// d_out layout (fp32, flat concat in return order)
#define OUT_E0      0       // 2048
#define OUT_E1      2048    // 1024
#define OUT_E2      3072    // 512
#define OUT_E3      3584    // 256
#define OUT_EMB     3840    // 256
#define OUT_C0      4096    // 6144
#define OUT_LSNR    10240   // 1
#define OUT_BUF_ERB 10241   // 32
#define OUT_BUF_DF  10273   // 192
#define OUT_HENC    10465   // 256  (total 10721)

// ws layout (floats)
#define WS_PART 0           // 48*256 partial cemb products
#define WS_GH   12288       // 768 gh = W_hh @ h + b_hh
#define WS_CNT  13056       // int counter (last-block detection)
#define WS_LACC 13057       // float lsnr dot accumulator

static __device__ __forceinline__ float sigm(float x) {
    return 1.0f / (1.0f + expf(-x));
}

// ---------------- KA -----------------------------------------------------------
// block 0     : zero cnt/lacc; e0 (in-block) -> e1 -> e2 -> e3 (pipelined weights)
// blocks 1..48: c0 (3 cols, in-block) -> c1 column -> W_dffc partial into ws
// blocks 49..96: gh rows (16 per block) into ws  [input-only, overlaps blk0 chain]
__global__ __launch_bounds__(256) void ka(
    const float* __restrict__ feat_erb, const float* __restrict__ feat_spec,
    const float* __restrict__ buf_erb0, const float* __restrict__ buf_df0,
    const float* __restrict__ h_enc,
    const float* __restrict__ W_erb0, const float* __restrict__ b_erb0,
    const float* __restrict__ W_erb1, const float* __restrict__ b_erb1,
    const float* __restrict__ W_erb2, const float* __restrict__ b_erb2,
    const float* __restrict__ W_erb3, const float* __restrict__ b_erb3,
    const float* __restrict__ W_df0,  const float* __restrict__ b_df0,
    const float* __restrict__ W_df1,  const float* __restrict__ b_df1,
    const float* __restrict__ W_dffc,
    const float* __restrict__ W_hh,   const float* __restrict__ b_hh,
    float* __restrict__ out, float* __restrict__ ws)
{
    const int blk = blockIdx.x, t = threadIdx.x;
    __shared__ float sW1[64 * 193];   // stride 193: conflict-free weight reads
    __shared__ float sW2[64 * 193];
    __shared__ __align__(16) float sA[2048];  // e0, later e2 (512)
    __shared__ __align__(16) float sB[1024];  // e1
    __shared__ float s_c0[192];
    __shared__ float s_c1[64];

    if (blk == 0) {
        if (t == 0) {                      // zero KB's counter/accumulator
            ((int*)ws)[WS_CNT] = 0;
            ws[WS_LACC] = 0.0f;
        }
        const int o = t & 63, wg = t >> 6;   // wg is wave-uniform
        float4 wbuf[12];

        // issue W1 HBM loads first; e0 computes under them
        {
            const float4* W1v = reinterpret_cast<const float4*>(W_erb1);
            #pragma unroll
            for (int j = 0; j < 12; ++j) wbuf[j] = W1v[t + 256 * j];
        }
        // ---- e0 in-block: thread t -> channel oc=t>>2, w in [8q, 8q+8) ----
        {
            const int oc = t >> 2, q = t & 3;
            const float* W = W_erb0 + oc * 6;
            const float b0 = b_erb0[oc];
            #pragma unroll
            for (int m = 0; m < 8; ++m) {
                int w_ = q * 8 + m;
                float a = b0;
                #pragma unroll
                for (int kw = 0; kw < 3; ++kw) {
                    int x = w_ + kw - 1;
                    if (x >= 0 && x < NB_ERB)
                        a += W[kw] * buf_erb0[x] + W[3 + kw] * feat_erb[x];
                }
                float v = fmaxf(a, 0.0f);
                sA[oc * 32 + w_] = v;
                out[OUT_E0 + oc * 32 + w_] = v;
            }
        }
        if (t < 32) out[OUT_BUF_ERB + t] = feat_erb[t];
        // store W1 to LDS, issue W2 loads
        {
            #pragma unroll
            for (int j = 0; j < 12; ++j) {
                int k4 = t + 256 * j;
                float* p = &sW1[(k4 / 48) * 193 + (k4 % 48) * 4];
                p[0] = wbuf[j].x; p[1] = wbuf[j].y; p[2] = wbuf[j].z; p[3] = wbuf[j].w;
            }
            const float4* W2v = reinterpret_cast<const float4*>(W_erb2);
            #pragma unroll
            for (int j = 0; j < 12; ++j) wbuf[j] = W2v[t + 256 * j];
        }
        __syncthreads();

        // ---- e1: o=t&63, w = wg*4+q ----
        {
            float bias = b_erb1[o];
            float a0 = bias, a1 = bias, a2 = bias, a3 = bias;
            const float* wrow = &sW1[o * 193];
            for (int i = 0; i < 64; ++i) {
                float w0 = wrow[i * 3], w1 = wrow[i * 3 + 1], w2 = wrow[i * 3 + 2];
                const float* e = &sA[i * 32 + wg * 8];
                float em1 = (wg == 0) ? 0.0f : e[-1];     // wave-uniform branch
                float4 v0 = *reinterpret_cast<const float4*>(e);
                float4 v1 = *reinterpret_cast<const float4*>(e + 4);
                a0 += w0 * em1  + w1 * v0.x + w2 * v0.y;
                a1 += w0 * v0.y + w1 * v0.z + w2 * v0.w;
                a2 += w0 * v0.w + w1 * v1.x + w2 * v1.y;
                a3 += w0 * v1.y + w1 * v1.z + w2 * v1.w;
            }
            float4 r = make_float4(fmaxf(a0, 0.f), fmaxf(a1, 0.f),
                                   fmaxf(a2, 0.f), fmaxf(a3, 0.f));
            reinterpret_cast<float4*>(&sB[o * 16])[wg] = r;
            reinterpret_cast<float4*>(out + OUT_E1)[o * 4 + wg] = r;
        }
        // write W2 to LDS, issue W3 loads
        {
            #pragma unroll
            for (int j = 0; j < 12; ++j) {
                int k4 = t + 256 * j;
                float* p = &sW2[(k4 / 48) * 193 + (k4 % 48) * 4];
                p[0] = wbuf[j].x; p[1] = wbuf[j].y; p[2] = wbuf[j].z; p[3] = wbuf[j].w;
            }
            const float4* W3v = reinterpret_cast<const float4*>(W_erb3);
            #pragma unroll
            for (int j = 0; j < 12; ++j) wbuf[j] = W3v[t + 256 * j];
        }
        __syncthreads();

        // ---- e2: w in {2wg, 2wg+1} ----
        {
            float bias = b_erb2[o];
            float a0 = bias, a1 = bias;
            const float* wrow = &sW2[o * 193];
            for (int i = 0; i < 64; ++i) {
                float w0 = wrow[i * 3], w1 = wrow[i * 3 + 1], w2 = wrow[i * 3 + 2];
                const float* e = &sB[i * 16 + wg * 4];
                float em1 = (wg == 0) ? 0.0f : e[-1];
                float4 v = *reinterpret_cast<const float4*>(e);
                a0 += w0 * em1 + w1 * v.x + w2 * v.y;
                a1 += w0 * v.y + w1 * v.z + w2 * v.w;
            }
            a0 = fmaxf(a0, 0.0f); a1 = fmaxf(a1, 0.0f);
            int w = 2 * wg;
            sA[o * 8 + w] = a0; sA[o * 8 + w + 1] = a1;   // e0 fully consumed pre-barrier
            out[OUT_E2 + o * 8 + w] = a0; out[OUT_E2 + o * 8 + w + 1] = a1;
        }
        // write W3 to LDS (sW1 free: last read before previous barrier)
        {
            #pragma unroll
            for (int j = 0; j < 12; ++j) {
                int k4 = t + 256 * j;
                float* p = &sW1[(k4 / 48) * 193 + (k4 % 48) * 4];
                p[0] = wbuf[j].x; p[1] = wbuf[j].y; p[2] = wbuf[j].z; p[3] = wbuf[j].w;
            }
        }
        __syncthreads();

        // ---- e3: w = wg ----
        {
            float a = b_erb3[o];
            const float* wrow = &sW1[o * 193];
            for (int i = 0; i < 64; ++i) {
                float w0 = wrow[i * 3], w1 = wrow[i * 3 + 1], w2 = wrow[i * 3 + 2];
                const float* e = &sA[i * 8 + 2 * wg];
                float em1 = (wg == 0) ? 0.0f : e[-1];
                a += w0 * em1 + w1 * e[0] + w2 * e[1];
            }
            out[OUT_E3 + o * 4 + wg] = fmaxf(a, 0.0f);
        }
    } else if (blk <= 48) {
        // ---- blocks 1..48: c0 (3 needed cols) -> c1 col w -> cemb partial ----
        const int w = blk - 1;
        if (blk == 1 && t < 192) out[OUT_BUF_DF + t] = feat_spec[t];
        if (t < 192) {
            const int i = t & 63, j = t >> 6;     // j = 0..2, X = 2w-1+j
            const int X = 2 * w - 1 + j;
            float v = 0.0f;
            if (X >= 0) {                          // X <= 95 always
                float acc = b_df0[i];
                const float* Wp = W_df0 + i * 12;  // [c][kt][kw]
                #pragma unroll
                for (int c = 0; c < 2; ++c)
                    #pragma unroll
                    for (int kw = 0; kw < 3; ++kw) {
                        int x = X + kw - 1;
                        if (x >= 0 && x < NB_DF) {
                            acc += Wp[c * 6 + kw]     * buf_df0[c * NB_DF + x];
                            acc += Wp[c * 6 + 3 + kw] * feat_spec[c * NB_DF + x];
                        }
                    }
                v = fmaxf(acc, 0.0f);
                if (j >= 1) out[OUT_C0 + i * NB_DF + X] = v;  // cols 2w, 2w+1
            }
            s_c0[i * 3 + j] = v;
        }
        __syncthreads();
        const int c = t >> 2, p = t & 3;
        float wloc[48];
        {
            const float4* Wv = reinterpret_cast<const float4*>(W_df1 + c * 192 + p * 48);
            #pragma unroll
            for (int q = 0; q < 12; ++q) {
                float4 v = Wv[q];
                wloc[4 * q] = v.x; wloc[4 * q + 1] = v.y;
                wloc[4 * q + 2] = v.z; wloc[4 * q + 3] = v.w;
            }
        }
        float acc = 0.0f;
        #pragma unroll
        for (int ii = 0; ii < 16; ++ii) {
            int i = p * 16 + ii;
            acc += wloc[ii * 3]     * s_c0[i * 3]
                 + wloc[ii * 3 + 1] * s_c0[i * 3 + 1]
                 + wloc[ii * 3 + 2] * s_c0[i * 3 + 2];
        }
        acc += __shfl_down(acc, 2, 4);
        acc += __shfl_down(acc, 1, 4);
        if (p == 0) s_c1[c] = fmaxf(acc + b_df1[c], 0.0f);
        __syncthreads();
        // thread t = output o: dot(W_dffc[o, w*64 : (w+1)*64], c1col)
        {
            const float4* Wp = reinterpret_cast<const float4*>(W_dffc + t * 3072 + w * 64);
            float a = 0.0f;
            #pragma unroll
            for (int q = 0; q < 16; ++q) {
                float4 v = Wp[q];
                a += v.x * s_c1[q * 4]     + v.y * s_c1[q * 4 + 1]
                   + v.z * s_c1[q * 4 + 2] + v.w * s_c1[q * 4 + 3];
            }
            ws[WS_PART + w * 256 + t] = a;
        }
    } else {
        // ---- blocks 49..96: gh = W_hh @ h_enc + b_hh (16 rows per block) ----
        const int wv = t >> 6, lane = t & 63;
        const int o0 = (blk - 49) * 16 + wv * 4;
        const float4 hv = *reinterpret_cast<const float4*>(h_enc + lane * 4);
        float r[4];
        #pragma unroll
        for (int j = 0; j < 4; ++j) {
            const float4 wr = *reinterpret_cast<const float4*>(W_hh + (o0 + j) * EMB + lane * 4);
            r[j] = wr.x * hv.x + wr.y * hv.y + wr.z * hv.z + wr.w * hv.w;
        }
        #pragma unroll
        for (int off = 32; off; off >>= 1) {
            #pragma unroll
            for (int j = 0; j < 4; ++j) r[j] += __shfl_down(r[j], off);
        }
        if (lane == 0) {
            #pragma unroll
            for (int j = 0; j < 4; ++j) ws[WS_GH + o0 + j] = r[j] + b_hh[o0 + j];
        }
    }
}

// ---------------- KB: x2 + gi + GRU + lsnr (64 blocks, last-block finish) ----
__global__ __launch_bounds__(256) void kb(
    const float* __restrict__ h_enc, const float* __restrict__ b_dffc,
    const float* __restrict__ W_ih,  const float* __restrict__ b_ih,
    const float* __restrict__ W_lsnr, const float* __restrict__ b_lsnr,
    float* __restrict__ out, float* __restrict__ ws)
{
    const int t = threadIdx.x, blk = blockIdx.x;
    __shared__ __align__(16) float s_x2[256];
    __shared__ float s_l[4];
    {
        float acc = b_dffc[t];
        #pragma unroll 8
        for (int w = 0; w < 48; ++w) acc += ws[WS_PART + w * 256 + t];
        float cemb = fmaxf(acc, 0.0f);
        float e3v = out[OUT_E3 + (t & 63) * 4 + (t >> 6)];
        s_x2[t] = e3v + cemb;
    }
    __syncthreads();
    const int wv = t >> 6, lane = t & 63;
    const int o = blk * 4 + wv;
    const float4 xv = *reinterpret_cast<const float4*>(&s_x2[lane * 4]);
    const float4 wir = *reinterpret_cast<const float4*>(W_ih + (o      ) * EMB + lane * 4);
    const float4 wiz = *reinterpret_cast<const float4*>(W_ih + (o + 256) * EMB + lane * 4);
    const float4 win = *reinterpret_cast<const float4*>(W_ih + (o + 512) * EMB + lane * 4);
    float air = wir.x * xv.x + wir.y * xv.y + wir.z * xv.z + wir.w * xv.w;
    float aiz = wiz.x * xv.x + wiz.y * xv.y + wiz.z * xv.z + wiz.w * xv.w;
    float ain = win.x * xv.x + win.y * xv.y + win.z * xv.z + win.w * xv.w;
    #pragma unroll
    for (int off = 32; off; off >>= 1) {
        air += __shfl_down(air, off);
        aiz += __shfl_down(aiz, off);
        ain += __shfl_down(ain, off);
    }
    if (lane == 0) {
        float r  = sigm(air + b_ih[o]       + ws[WS_GH + o]);
        float z  = sigm(aiz + b_ih[o + 256] + ws[WS_GH + 256 + o]);
        float ng = tanhf(ain + b_ih[o + 512] + r * ws[WS_GH + 512 + o]);
        float h  = (1.0f - z) * ng + z * h_enc[o];
        out[OUT_EMB  + o] = h;
        out[OUT_HENC + o] = h;
        s_l[wv] = h * W_lsnr[o];
    }
    __syncthreads();
    if (t == 0) {
        float p = s_l[0] + s_l[1] + s_l[2] + s_l[3];
        atomicAdd(&ws[WS_LACC], p);
        __threadfence();                              // acc visible before cnt
        int old = atomicAdd(&((int*)ws)[WS_CNT], 1);
        if (old == 63) {                              // last block: finish lsnr
            __threadfence();
            float tot = atomicAdd(&ws[WS_LACC], 0.0f);   // atomic read, full sum
            out[OUT_LSNR] = sigm(tot + b_lsnr[0]) * 50.0f - 15.0f;
        }
    }
}

extern "C" void kernel_launch(void* const* d_in, const int* in_sizes, int n_in,
                              void* d_out, int out_size, void* d_ws, size_t ws_size,
                              hipStream_t stream) {
    (void)in_sizes; (void)n_in; (void)out_size; (void)ws_size;
    const float* feat_erb  = (const float*)d_in[0];
    const float* feat_spec = (const float*)d_in[1];
    const float* buf_erb0  = (const float*)d_in[2];
    const float* buf_df0   = (const float*)d_in[3];
    const float* h_enc     = (const float*)d_in[4];
    const float* W_erb0    = (const float*)d_in[5];
    const float* b_erb0    = (const float*)d_in[6];
    const float* W_erb1    = (const float*)d_in[7];
    const float* b_erb1    = (const float*)d_in[8];
    const float* W_erb2    = (const float*)d_in[9];
    const float* b_erb2    = (const float*)d_in[10];
    const float* W_erb3    = (const float*)d_in[11];
    const float* b_erb3    = (const float*)d_in[12];
    const float* W_df0     = (const float*)d_in[13];
    const float* b_df0     = (const float*)d_in[14];
    const float* W_df1     = (const float*)d_in[15];
    const float* b_df1     = (const float*)d_in[16];
    const float* W_dffc    = (const float*)d_in[17];
    const float* b_dffc    = (const float*)d_in[18];
    const float* W_ih      = (const float*)d_in[19];
    const float* b_ih      = (const float*)d_in[20];
    const float* W_hh      = (const float*)d_in[21];
    const float* b_hh      = (const float*)d_in[22];
    const float* W_lsnr    = (const float*)d_in[23];
    const float* b_lsnr    = (const float*)d_in[24];
    float* out = (float*)d_out;
    float* ws  = (float*)d_ws;

    hipLaunchKernelGGL(ka, dim3(97), dim3(256), 0, stream,
                       feat_erb, feat_spec, buf_erb0, buf_df0, h_enc,
                       W_erb0, b_erb0, W_erb1, b_erb1, W_erb2, b_erb2,
                       W_erb3, b_erb3, W_df0, b_df0, W_df1, b_df1,
                       W_dffc, W_hh, b_hh, out, ws);
    hipLaunchKernelGGL(kb, dim3(64), dim3(256), 0, stream,
                       h_enc, b_dffc, W_ih, b_ih, W_lsnr, b_lsnr, out, ws);
}

// Round 6
// 126.820 us; speedup vs baseline: 1.0079x; 1.0079x over previous
//
#include <hip/hip_runtime.h>
#include <math.h>

#define NB_ERB 32
#define NB_DF 96
#define EMB 256

// d_out layout (fp32, flat concat in return order)
#define OUT_E0      0       // 2048
#define OUT_E1      2048    // 1024
#define OUT_E2      3072    // 512
#define OUT_E3      3584    // 256
#define OUT_EMB     3840    // 256
#define OUT_C0      4096    // 6144
#define OUT_LSNR    10240   // 1
#define OUT_BUF_ERB 10241   // 32
#define OUT_BUF_DF  10273   // 192
#define OUT_HENC    10465   // 256  (total 10721)

// ws layout (floats)
#define WS_PART 0           // 48*256 partial cemb products

static __device__ __forceinline__ float sigm(float x) {
    return 1.0f / (1.0f + expf(-x));
}

// ---------------- KA: both conv chains ---------------------------------------
// block 0     : e0 (in-block) -> e1 -> e2 -> e3 (pipelined weight staging)
// blocks 1..48: c0 (3 cols, in-block) -> c1 column -> W_dffc partial into ws
__global__ __launch_bounds__(256) void ka(
    const float* __restrict__ feat_erb, const float* __restrict__ feat_spec,
    const float* __restrict__ buf_erb0, const float* __restrict__ buf_df0,
    const float* __restrict__ W_erb0, const float* __restrict__ b_erb0,
    const float* __restrict__ W_erb1, const float* __restrict__ b_erb1,
    const float* __restrict__ W_erb2, const float* __restrict__ b_erb2,
    const float* __restrict__ W_erb3, const float* __restrict__ b_erb3,
    const float* __restrict__ W_df0,  const float* __restrict__ b_df0,
    const float* __restrict__ W_df1,  const float* __restrict__ b_df1,
    const float* __restrict__ W_dffc,
    float* __restrict__ out, float* __restrict__ ws)
{
    const int blk = blockIdx.x, t = threadIdx.x;
    __shared__ float sW1[64 * 193];   // stride 193: conflict-free weight reads
    __shared__ float sW2[64 * 193];
    __shared__ __align__(16) float sA[2048];  // e0, later e2 (512)
    __shared__ __align__(16) float sB[1024];  // e1
    __shared__ float s_c0[192];
    __shared__ float s_c1[64];

    if (blk == 0) {
        const int o = t & 63, wg = t >> 6;   // wg is wave-uniform
        float4 wbuf[12];

        // issue W1 HBM loads first; e0 computes under them
        {
            const float4* W1v = reinterpret_cast<const float4*>(W_erb1);
            #pragma unroll
            for (int j = 0; j < 12; ++j) wbuf[j] = W1v[t + 256 * j];
        }
        // ---- e0 in-block: thread t -> channel oc=t>>2, w in [8q, 8q+8) ----
        {
            const int oc = t >> 2, q = t & 3;
            const float* W = W_erb0 + oc * 6;
            const float b0 = b_erb0[oc];
            #pragma unroll
            for (int m = 0; m < 8; ++m) {
                int w_ = q * 8 + m;
                float a = b0;
                #pragma unroll
                for (int kw = 0; kw < 3; ++kw) {
                    int x = w_ + kw - 1;
                    if (x >= 0 && x < NB_ERB)
                        a += W[kw] * buf_erb0[x] + W[3 + kw] * feat_erb[x];
                }
                float v = fmaxf(a, 0.0f);
                sA[oc * 32 + w_] = v;
                out[OUT_E0 + oc * 32 + w_] = v;
            }
        }
        if (t < 32) out[OUT_BUF_ERB + t] = feat_erb[t];
        // store W1 to LDS, issue W2 loads
        {
            #pragma unroll
            for (int j = 0; j < 12; ++j) {
                int k4 = t + 256 * j;
                float* p = &sW1[(k4 / 48) * 193 + (k4 % 48) * 4];
                p[0] = wbuf[j].x; p[1] = wbuf[j].y; p[2] = wbuf[j].z; p[3] = wbuf[j].w;
            }
            const float4* W2v = reinterpret_cast<const float4*>(W_erb2);
            #pragma unroll
            for (int j = 0; j < 12; ++j) wbuf[j] = W2v[t + 256 * j];
        }
        __syncthreads();

        // ---- e1: o=t&63, w = wg*4+q ----
        {
            float bias = b_erb1[o];
            float a0 = bias, a1 = bias, a2 = bias, a3 = bias;
            const float* wrow = &sW1[o * 193];
            for (int i = 0; i < 64; ++i) {
                float w0 = wrow[i * 3], w1 = wrow[i * 3 + 1], w2 = wrow[i * 3 + 2];
                const float* e = &sA[i * 32 + wg * 8];
                float em1 = (wg == 0) ? 0.0f : e[-1];     // wave-uniform branch
                float4 v0 = *reinterpret_cast<const float4*>(e);
                float4 v1 = *reinterpret_cast<const float4*>(e + 4);
                a0 += w0 * em1  + w1 * v0.x + w2 * v0.y;
                a1 += w0 * v0.y + w1 * v0.z + w2 * v0.w;
                a2 += w0 * v0.w + w1 * v1.x + w2 * v1.y;
                a3 += w0 * v1.y + w1 * v1.z + w2 * v1.w;
            }
            float4 r = make_float4(fmaxf(a0, 0.f), fmaxf(a1, 0.f),
                                   fmaxf(a2, 0.f), fmaxf(a3, 0.f));
            reinterpret_cast<float4*>(&sB[o * 16])[wg] = r;
            reinterpret_cast<float4*>(out + OUT_E1)[o * 4 + wg] = r;
        }
        // write W2 to LDS, issue W3 loads
        {
            #pragma unroll
            for (int j = 0; j < 12; ++j) {
                int k4 = t + 256 * j;
                float* p = &sW2[(k4 / 48) * 193 + (k4 % 48) * 4];
                p[0] = wbuf[j].x; p[1] = wbuf[j].y; p[2] = wbuf[j].z; p[3] = wbuf[j].w;
            }
            const float4* W3v = reinterpret_cast<const float4*>(W_erb3);
            #pragma unroll
            for (int j = 0; j < 12; ++j) wbuf[j] = W3v[t + 256 * j];
        }
        __syncthreads();

        // ---- e2: w in {2wg, 2wg+1} ----
        {
            float bias = b_erb2[o];
            float a0 = bias, a1 = bias;
            const float* wrow = &sW2[o * 193];
            for (int i = 0; i < 64; ++i) {
                float w0 = wrow[i * 3], w1 = wrow[i * 3 + 1], w2 = wrow[i * 3 + 2];
                const float* e = &sB[i * 16 + wg * 4];
                float em1 = (wg == 0) ? 0.0f : e[-1];
                float4 v = *reinterpret_cast<const float4*>(e);
                a0 += w0 * em1 + w1 * v.x + w2 * v.y;
                a1 += w0 * v.y + w1 * v.z + w2 * v.w;
            }
            a0 = fmaxf(a0, 0.0f); a1 = fmaxf(a1, 0.0f);
            int w = 2 * wg;
            sA[o * 8 + w] = a0; sA[o * 8 + w + 1] = a1;   // e0 fully consumed pre-barrier
            out[OUT_E2 + o * 8 + w] = a0; out[OUT_E2 + o * 8 + w + 1] = a1;
        }
        // write W3 to LDS (sW1 free: last read before previous barrier)
        {
            #pragma unroll
            for (int j = 0; j < 12; ++j) {
                int k4 = t + 256 * j;
                float* p = &sW1[(k4 / 48) * 193 + (k4 % 48) * 4];
                p[0] = wbuf[j].x; p[1] = wbuf[j].y; p[2] = wbuf[j].z; p[3] = wbuf[j].w;
            }
        }
        __syncthreads();

        // ---- e3: w = wg ----
        {
            float a = b_erb3[o];
            const float* wrow = &sW1[o * 193];
            for (int i = 0; i < 64; ++i) {
                float w0 = wrow[i * 3], w1 = wrow[i * 3 + 1], w2 = wrow[i * 3 + 2];
                const float* e = &sA[i * 8 + 2 * wg];
                float em1 = (wg == 0) ? 0.0f : e[-1];
                a += w0 * em1 + w1 * e[0] + w2 * e[1];
            }
            out[OUT_E3 + o * 4 + wg] = fmaxf(a, 0.0f);
        }
    } else {
        // ---- blocks 1..48: c0 (3 needed cols) -> c1 col w -> cemb partial ----
        const int w = blk - 1;
        if (blk == 1 && t < 192) out[OUT_BUF_DF + t] = feat_spec[t];
        if (t < 192) {
            const int i = t & 63, j = t >> 6;     // j = 0..2, X = 2w-1+j
            const int X = 2 * w - 1 + j;
            float v = 0.0f;
            if (X >= 0) {                          // X <= 95 always
                float acc = b_df0[i];
                const float* Wp = W_df0 + i * 12;  // [c][kt][kw]
                #pragma unroll
                for (int c = 0; c < 2; ++c)
                    #pragma unroll
                    for (int kw = 0; kw < 3; ++kw) {
                        int x = X + kw - 1;
                        if (x >= 0 && x < NB_DF) {
                            acc += Wp[c * 6 + kw]     * buf_df0[c * NB_DF + x];
                            acc += Wp[c * 6 + 3 + kw] * feat_spec[c * NB_DF + x];
                        }
                    }
                v = fmaxf(acc, 0.0f);
                if (j >= 1) out[OUT_C0 + i * NB_DF + X] = v;  // cols 2w, 2w+1
            }
            s_c0[i * 3 + j] = v;
        }
        __syncthreads();
        const int c = t >> 2, p = t & 3;
        float wloc[48];
        {
            const float4* Wv = reinterpret_cast<const float4*>(W_df1 + c * 192 + p * 48);
            #pragma unroll
            for (int q = 0; q < 12; ++q) {
                float4 v = Wv[q];
                wloc[4 * q] = v.x; wloc[4 * q + 1] = v.y;
                wloc[4 * q + 2] = v.z; wloc[4 * q + 3] = v.w;
            }
        }
        float acc = 0.0f;
        #pragma unroll
        for (int ii = 0; ii < 16; ++ii) {
            int i = p * 16 + ii;
            acc += wloc[ii * 3]     * s_c0[i * 3]
                 + wloc[ii * 3 + 1] * s_c0[i * 3 + 1]
                 + wloc[ii * 3 + 2] * s_c0[i * 3 + 2];
        }
        acc += __shfl_down(acc, 2, 4);
        acc += __shfl_down(acc, 1, 4);
        if (p == 0) s_c1[c] = fmaxf(acc + b_df1[c], 0.0f);
        __syncthreads();
        // thread t = output o: dot(W_dffc[o, w*64 : (w+1)*64], c1col)
        {
            const float4* Wp = reinterpret_cast<const float4*>(W_dffc + t * 3072 + w * 64);
            float a = 0.0f;
            #pragma unroll
            for (int q = 0; q < 16; ++q) {
                float4 v = Wp[q];
                a += v.x * s_c1[q * 4]     + v.y * s_c1[q * 4 + 1]
                   + v.z * s_c1[q * 4 + 2] + v.w * s_c1[q * 4 + 3];
            }
            ws[WS_PART + w * 256 + t] = a;
        }
    }
}

// ---------------- KB: x2 + gi + gh + GRU (64 blocks) -------------------------
// each block recomputes x2 (L2-resident partials); each wave owns one output o
// and computes all 6 dot-256 products (gi r/z/n + gh r/z/n) itself.
__global__ __launch_bounds__(256) void kb(
    const float* __restrict__ h_enc, const float* __restrict__ b_dffc,
    const float* __restrict__ W_ih,  const float* __restrict__ b_ih,
    const float* __restrict__ W_hh,  const float* __restrict__ b_hh,
    float* __restrict__ out, const float* __restrict__ ws)
{
    const int t = threadIdx.x, blk = blockIdx.x;
    __shared__ __align__(16) float s_x2[256];
    {
        float acc = b_dffc[t];
        #pragma unroll 8
        for (int w = 0; w < 48; ++w) acc += ws[WS_PART + w * 256 + t];
        float cemb = fmaxf(acc, 0.0f);
        float e3v = out[OUT_E3 + (t & 63) * 4 + (t >> 6)];
        s_x2[t] = e3v + cemb;
    }
    __syncthreads();
    const int wv = t >> 6, lane = t & 63;
    const int o = blk * 4 + wv;
    const float4 xv = *reinterpret_cast<const float4*>(&s_x2[lane * 4]);
    const float4 hv = *reinterpret_cast<const float4*>(h_enc + lane * 4);
    const float4 wir = *reinterpret_cast<const float4*>(W_ih + (o      ) * EMB + lane * 4);
    const float4 wiz = *reinterpret_cast<const float4*>(W_ih + (o + 256) * EMB + lane * 4);
    const float4 win = *reinterpret_cast<const float4*>(W_ih + (o + 512) * EMB + lane * 4);
    const float4 whr = *reinterpret_cast<const float4*>(W_hh + (o      ) * EMB + lane * 4);
    const float4 whz = *reinterpret_cast<const float4*>(W_hh + (o + 256) * EMB + lane * 4);
    const float4 whn = *reinterpret_cast<const float4*>(W_hh + (o + 512) * EMB + lane * 4);
    float air = wir.x * xv.x + wir.y * xv.y + wir.z * xv.z + wir.w * xv.w;
    float aiz = wiz.x * xv.x + wiz.y * xv.y + wiz.z * xv.z + wiz.w * xv.w;
    float ain = win.x * xv.x + win.y * xv.y + win.z * xv.z + win.w * xv.w;
    float ahr = whr.x * hv.x + whr.y * hv.y + whr.z * hv.z + whr.w * hv.w;
    float ahz = whz.x * hv.x + whz.y * hv.y + whz.z * hv.z + whz.w * hv.w;
    float ahn = whn.x * hv.x + whn.y * hv.y + whn.z * hv.z + whn.w * hv.w;
    #pragma unroll
    for (int off = 32; off; off >>= 1) {
        air += __shfl_down(air, off);
        aiz += __shfl_down(aiz, off);
        ain += __shfl_down(ain, off);
        ahr += __shfl_down(ahr, off);
        ahz += __shfl_down(ahz, off);
        ahn += __shfl_down(ahn, off);
    }
    if (lane == 0) {
        float r  = sigm(air + b_ih[o]       + ahr + b_hh[o]);
        float z  = sigm(aiz + b_ih[o + 256] + ahz + b_hh[o + 256]);
        float ng = tanhf(ain + b_ih[o + 512] + r * (ahn + b_hh[o + 512]));
        float h  = (1.0f - z) * ng + z * h_enc[o];
        out[OUT_EMB  + o] = h;
        out[OUT_HENC + o] = h;
    }
}

// ---------------- KC: lsnr ---------------------------------------------------
__global__ __launch_bounds__(256) void kc(
    const float* __restrict__ W_lsnr, const float* __restrict__ b_lsnr,
    float* __restrict__ out)
{
    const int t = threadIdx.x;
    __shared__ float s[4];
    float v = out[OUT_EMB + t] * W_lsnr[t];
    #pragma unroll
    for (int off = 32; off; off >>= 1) v += __shfl_down(v, off);
    if ((t & 63) == 0) s[t >> 6] = v;
    __syncthreads();
    if (t == 0)
        out[OUT_LSNR] = sigm(s[0] + s[1] + s[2] + s[3] + b_lsnr[0]) * 50.0f - 15.0f;
}

extern "C" void kernel_launch(void* const* d_in, const int* in_sizes, int n_in,
                              void* d_out, int out_size, void* d_ws, size_t ws_size,
                              hipStream_t stream) {
    (void)in_sizes; (void)n_in; (void)out_size; (void)ws_size;
    const float* feat_erb  = (const float*)d_in[0];
    const float* feat_spec = (const float*)d_in[1];
    const float* buf_erb0  = (const float*)d_in[2];
    const float* buf_df0   = (const float*)d_in[3];
    const float* h_enc     = (const float*)d_in[4];
    const float* W_erb0    = (const float*)d_in[5];
    const float* b_erb0    = (const float*)d_in[6];
    const float* W_erb1    = (const float*)d_in[7];
    const float* b_erb1    = (const float*)d_in[8];
    const float* W_erb2    = (const float*)d_in[9];
    const float* b_erb2    = (const float*)d_in[10];
    const float* W_erb3    = (const float*)d_in[11];
    const float* b_erb3    = (const float*)d_in[12];
    const float* W_df0     = (const float*)d_in[13];
    const float* b_df0     = (const float*)d_in[14];
    const float* W_df1     = (const float*)d_in[15];
    const float* b_df1     = (const float*)d_in[16];
    const float* W_dffc    = (const float*)d_in[17];
    const float* b_dffc    = (const float*)d_in[18];
    const float* W_ih      = (const float*)d_in[19];
    const float* b_ih      = (const float*)d_in[20];
    const float* W_hh      = (const float*)d_in[21];
    const float* b_hh      = (const float*)d_in[22];
    const float* W_lsnr    = (const float*)d_in[23];
    const float* b_lsnr    = (const float*)d_in[24];
    float* out = (float*)d_out;
    float* ws  = (float*)d_ws;

    hipLaunchKernelGGL(ka, dim3(49), dim3(256), 0, stream,
                       feat_erb, feat_spec, buf_erb0, buf_df0,
                       W_erb0, b_erb0, W_erb1, b_erb1, W_erb2, b_erb2,
                       W_erb3, b_erb3, W_df0, b_df0, W_df1, b_df1,
                       W_dffc, out, ws);
    hipLaunchKernelGGL(kb, dim3(64), dim3(256), 0, stream,
                       h_enc, b_dffc, W_ih, b_ih, W_hh, b_hh, out, ws);
    hipLaunchKernelGGL(kc, dim3(1), dim3(256), 0, stream,
                       W_lsnr, b_lsnr, out);
}